// Round 20
// baseline (87.119 us; speedup 1.0000x reference)
//
#include <hip/hip_runtime.h>
#include <math.h>

typedef unsigned short u16;
typedef _Float16 f16;
typedef __attribute__((ext_vector_type(8))) _Float16 f16x8;
typedef __attribute__((ext_vector_type(4))) float f32x4;

#define B_  4
#define T_  1024
#define D_  512
#define H_  8
#define DK_ 64
#define P_  2047

#define MFMAH(a, b, c) __builtin_amdgcn_mfma_f32_16x16x32_f16(a, b, c, 0, 0, 0)

__device__ __forceinline__ u16 f2hbits(float x) {
    union { f16 h; u16 u; } cv; cv.h = (f16)x; return cv.u;
}

__device__ __forceinline__ void gload_lds16(const u16* g, u16* l) {
    __builtin_amdgcn_global_load_lds(
        (const __attribute__((address_space(1))) void*)g,
        (__attribute__((address_space(3))) void*)l, 16, 0, 0);
}

__device__ __forceinline__ int swz8(int row, int colbase) {   // colbase % 8 == 0
    return row * 64 + (((colbase >> 3) ^ (row & 7)) << 3);
}

// ---------------------------------------------------------------------------
// One-shot conversion, BLOCK-UNIFORM segments: each block owns 1024
// contiguous float4-chunks of exactly one tensor (SALU-resolved once),
// inner loop = 4 independent stream iterations. Replaces the per-element
// 9-way branch ladder (round-14 form: 13 us @ 3.5 TB/s, 55% of achievable).
// Blocks: 0-511 q | 512-1023 k | 1024-1535 v | 1536-1791 pe | 1792+ weights.
// ---------------------------------------------------------------------------
__global__ __launch_bounds__(256)
void conv_all(const float* __restrict__ q, const float* __restrict__ k,
              const float* __restrict__ v, const float* __restrict__ pe,
              const float* __restrict__ wq, const float* __restrict__ wk,
              const float* __restrict__ wv, const float* __restrict__ wp,
              const float* __restrict__ wo,
              u16* qs, u16* ks, u16* vs, u16* pes,
              u16* wqs, u16* wks, u16* wvs, u16* wps, u16* wos)
{
    const int bx = blockIdx.x;
    const float* src; u16* dst; int base, limit;
    if (bx < 512)       { src = q;  dst = qs;  base = bx * 1024;          limit = 524288; }
    else if (bx < 1024) { src = k;  dst = ks;  base = (bx - 512) * 1024;  limit = 524288; }
    else if (bx < 1536) { src = v;  dst = vs;  base = (bx - 1024) * 1024; limit = 524288; }
    else if (bx < 1792) { src = pe; dst = pes; base = (bx - 1536) * 1024; limit = 262016; }
    else {
        int wb = bx - 1792, widx = wb >> 6;
        base = (wb & 63) * 1024; limit = 65536;
        src = widx == 0 ? wq : widx == 1 ? wk : widx == 2 ? wv
            : widx == 3 ? wp : wo;
        dst = widx == 0 ? wqs : widx == 1 ? wks : widx == 2 ? wvs
            : widx == 3 ? wps : wos;
    }
    #pragma unroll
    for (int it = 0; it < 4; ++it) {
        int off = base + it * 256 + threadIdx.x;
        if (off < limit) {
            float4 x = *(const float4*)(src + (size_t)off * 4);
            union { f16 h[4]; uint2 u2; } cv;
            cv.h[0] = (f16)x.x; cv.h[1] = (f16)x.y;
            cv.h[2] = (f16)x.z; cv.h[3] = (f16)x.w;
            *(uint2*)(dst + (size_t)off * 4) = cv.u2;
        }
    }
}

// ---------------------------------------------------------------------------
// FP16 GEMM core, COUNTED-VMCNT DOUBLE-BUFFER (round-14 validated):
// stage tile t+1 BEFORE computing tile t; s_waitcnt vmcnt(8) (never 0 in
// the loop) + raw s_barrier — next tile's 8 gload_lds stay in flight
// across the barrier through the MFMA phase. BM=128 BN=128 BK=64, 64 KB LDS.
// ---------------------------------------------------------------------------
__device__ __forceinline__ void gemm_core(
    const u16* __restrict__ A, const u16* __restrict__ Bw,
    int bm, int bn, int M, f32x4 (&acc)[4][4],
    u16 (&sA)[2][128][64], u16 (&sB)[2][128][64])
{
    const int tid = threadIdx.x;
    const int ln = tid & 63, w = tid >> 6;
    const int arow = ln & 15, kseg = ln >> 4;
    const int wr = w >> 1, wc = w & 1;

    auto stage = [&](int k0, int buf) {
        #pragma unroll
        for (int it = 0; it < 4; ++it) {               // A: 1024 chunks
            int ch = it * 256 + tid;
            int r = ch >> 3, j = ch & 7;
            int rm = bm + r; if (rm > M - 1) rm = M - 1;
            gload_lds16(A + (size_t)rm * 512 + k0 + ((j ^ (r & 7)) << 3),
                        &sA[buf][0][0] + ch * 8);
        }
        #pragma unroll
        for (int it = 0; it < 4; ++it) {               // B: 1024 chunks
            int ch = it * 256 + tid;
            int r = ch >> 3, j = ch & 7;
            gload_lds16(Bw + (size_t)(bn + r) * 512 + k0 + ((j ^ (r & 7)) << 3),
                        &sB[buf][0][0] + ch * 8);
        }
    };

    stage(0, 0);
    for (int t = 0; t < 8; ++t) {
        const int cur = t & 1;
        if (t < 7) {
            stage((t + 1) * 64, cur ^ 1);
            asm volatile("s_waitcnt vmcnt(8)" ::: "memory");
        } else {
            asm volatile("s_waitcnt vmcnt(0)" ::: "memory");
        }
        __builtin_amdgcn_sched_barrier(0);
        __builtin_amdgcn_s_barrier();

        f16x8 af[4][2], bf[4][2];
        #pragma unroll
        for (int mi = 0; mi < 4; ++mi) {
            int row = wr * 64 + mi * 16 + arow;
            #pragma unroll
            for (int kc = 0; kc < 2; ++kc)
                af[mi][kc] = *(const f16x8*)
                    (&sA[cur][row][0] + ((((kc << 2) | kseg) ^ (row & 7)) << 3));
        }
        #pragma unroll
        for (int nj = 0; nj < 4; ++nj) {
            int row = wc * 64 + nj * 16 + arow;
            #pragma unroll
            for (int kc = 0; kc < 2; ++kc)
                bf[nj][kc] = *(const f16x8*)
                    (&sB[cur][row][0] + ((((kc << 2) | kseg) ^ (row & 7)) << 3));
        }
        __builtin_amdgcn_s_setprio(1);
        #pragma unroll
        for (int mi = 0; mi < 4; ++mi)
            #pragma unroll
            for (int nj = 0; nj < 4; ++nj)
                #pragma unroll
                for (int kc = 0; kc < 2; ++kc)
                    acc[mi][nj] = MFMAH(af[mi][kc], bf[nj][kc], acc[mi][nj]);
        __builtin_amdgcn_s_setprio(0);

        asm volatile("" ::: "memory");
        __builtin_amdgcn_s_barrier();   // raw: orders slot reuse, no drain
        asm volatile("" ::: "memory");
    }
}

// ---------------------------------------------------------------------------
// Merged projection GEMM: q/k/v/pe in one launch. grid = (4, 112).
// seg0 emits qu = (q+u)/8 and qv = (q+v)/8 as fp16 head-major.
// ---------------------------------------------------------------------------
__global__ __launch_bounds__(256, 2)
void gemm_qkvp(const u16* __restrict__ qs, const u16* __restrict__ ks,
               const u16* __restrict__ vs, const u16* __restrict__ pes,
               const u16* __restrict__ wqs, const u16* __restrict__ wks,
               const u16* __restrict__ wvs, const u16* __restrict__ wps,
               const float* __restrict__ bq, const float* __restrict__ bk,
               const float* __restrict__ bv,
               const float* __restrict__ pbu, const float* __restrict__ pbv,
               u16* __restrict__ qub, u16* __restrict__ qvb,
               u16* __restrict__ kh, u16* __restrict__ vt, u16* __restrict__ ph)
{
    __shared__ u16 sA[2][128][64];
    __shared__ u16 sB[2][128][64];

    const int by = blockIdx.y;
    const u16 *A, *Bw; const float* bias;
    int seg, bm, M, Tn;
    if (by < 32)      { seg=0; bm=by*128;       A=qs;  Bw=wqs; bias=bq;      M=4096; Tn=T_; }
    else if (by < 64) { seg=1; bm=(by-32)*128;  A=ks;  Bw=wks; bias=bk;      M=4096; Tn=T_; }
    else if (by < 96) { seg=2; bm=(by-64)*128;  A=vs;  Bw=wvs; bias=bv;      M=4096; Tn=T_; }
    else              { seg=3; bm=(by-96)*128;  A=pes; Bw=wps; bias=nullptr; M=P_;   Tn=P_; }
    const int bn = blockIdx.x * 128;

    f32x4 acc[4][4] = {};
    gemm_core(A, Bw, bm, bn, M, acc, sA, sB);

    const int tid = threadIdx.x;
    const int ln = tid & 63, w = tid >> 6;
    const int arow = ln & 15, kseg = ln >> 4;
    const int wr = w >> 1, wc = w & 1;

    float bv0[4];
    #pragma unroll
    for (int nj = 0; nj < 4; ++nj)
        bv0[nj] = bias ? bias[bn + wc * 64 + nj * 16 + arow] : 0.f;

    #pragma unroll
    for (int mi = 0; mi < 4; ++mi)
        #pragma unroll
        for (int r = 0; r < 4; ++r) {
            int m = bm + wr * 64 + mi * 16 + kseg * 4 + r;
            if (m >= M) continue;
            #pragma unroll
            for (int nj = 0; nj < 4; ++nj) {
                int n = bn + wc * 64 + nj * 16 + arow;
                float val = acc[mi][nj][r] + bv0[nj];
                if (seg == 0) {
                    int bb = m >> 10, t = m & 1023;
                    int hh = n >> 6, d = n & 63;
                    size_t off = ((size_t)(bb * H_ + hh) * T_ + t) * 64 + d;
                    qub[off] = f2hbits((val + pbu[hh * 64 + d]) * 0.125f);
                    qvb[off] = f2hbits((val + pbv[hh * 64 + d]) * 0.125f);
                } else if (seg == 2) {
                    int bb = m >> 10, t = m & 1023;
                    int hh = n >> 6, d = n & 63;
                    vt[((size_t)(bb * H_ + hh) * 64 + d) * T_ + t] = f2hbits(val);
                } else {
                    int bb = (Tn == T_) ? (m >> 10) : 0;
                    int t = m - bb * Tn;
                    int hh = n >> 6, d = n & 63;
                    size_t off = ((size_t)(bb * H_ + hh) * Tn + t) * 64 + d;
                    if (seg == 1) kh[off] = f2hbits(val);
                    else          ph[off] = f2hbits(val);
                }
            }
        }
}

// ---------------------------------------------------------------------------
// Output projection (fp32 out)
// ---------------------------------------------------------------------------
__global__ __launch_bounds__(256, 2)
void gemm_out(const u16* __restrict__ A, const u16* __restrict__ Bw,
              const float* __restrict__ bias, float* __restrict__ C)
{
    __shared__ u16 sA[2][128][64];
    __shared__ u16 sB[2][128][64];
    const int bn = blockIdx.x * 128;
    const int bm = blockIdx.y * 128;
    f32x4 acc[4][4] = {};
    gemm_core(A, Bw, bm, bn, 4096, acc, sA, sB);

    const int tid = threadIdx.x;
    const int ln = tid & 63, w = tid >> 6;
    const int arow = ln & 15, kseg = ln >> 4;
    const int wr = w >> 1, wc = w & 1;
    #pragma unroll
    for (int mi = 0; mi < 4; ++mi)
        #pragma unroll
        for (int r = 0; r < 4; ++r) {
            int m = bm + wr * 64 + mi * 16 + kseg * 4 + r;
            #pragma unroll
            for (int nj = 0; nj < 4; ++nj) {
                int n = bn + wc * 64 + nj * 16 + arow;
                C[(size_t)m * 512 + n] = acc[mi][nj][r] + bias[n];
            }
        }
}

// ---------------------------------------------------------------------------
// Fused relative-position attention — round-12/14 validated configuration.
// fp16, fixed-max softmax, counted-vmcnt pipeline (3-slot K/P rings,
// prefetch distance 2, raw s_barrier; V loads issued first each iter).
// 256 threads / 4 waves: occupancy-raising variants all failed —
// more blocks (r8), K-split x2 (r10), 512-thread blocks (r16: 71 us).
// __launch_bounds__(256,2): do NOT raise — (256,4) caps VGPR at 64 ->
// 400 MB scratch spill (round 7, 2.7x slowdown).
// ---------------------------------------------------------------------------
__global__ __launch_bounds__(256, 2)
void relattn_mfma(const u16* __restrict__ qub, const u16* __restrict__ qvb,
                  const u16* __restrict__ kh, const u16* __restrict__ vt,
                  const u16* __restrict__ ph,
                  u16* __restrict__ ao)
{
    __shared__ u16 s_k[3][64][64];      // [slot][k][d]   24 KB ring
    __shared__ u16 s_p[3][64][64];      // [slot][j][d]   24 KB ring
    __shared__ u16 s_pp[4][16][64];     // wave-private P tiles  8 KB

    const int tid = threadIdx.x;
    const int ln  = tid & 63;
    const int w   = tid >> 6;
    const int arow = ln & 15;
    const int kseg = ln >> 4;

    const int lg = ((blockIdx.x & 7) << 6) | (blockIdx.x >> 3);
    const int qt = lg & 15, h = (lg >> 4) & 7, b = lg >> 7;
    const int q0 = qt * 64;

    const size_t kvbase = (size_t)(b * H_ + h) * T_ * 64;
    const size_t vtbase = (size_t)(b * H_ + h) * 64 * T_;
    const size_t pbase  = (size_t)h * P_ * 64;
    const int jb0 = 960 - q0;

    f16x8 qu[2], qv[2];
    {
        const u16* qb = qub + kvbase + (size_t)(q0 + w * 16 + arow) * 64;
        const u16* vb = qvb + kvbase + (size_t)(q0 + w * 16 + arow) * 64;
        #pragma unroll
        for (int c = 0; c < 2; ++c) {
            qu[c] = *(const f16x8*)(qb + c * 32 + kseg * 8);
            qv[c] = *(const f16x8*)(vb + c * 32 + kseg * 8);
        }
    }

    f32x4 o_[4] = {};
    float l_run[4] = {};

    auto stage_k = [&](int kt, int slot) {
        #pragma unroll
        for (int it = 0; it < 2; ++it) {
            int idx = tid + it * 256;
            int r = idx >> 3, ch = idx & 7;
            const u16* src = kh + kvbase + (size_t)(kt * 64 + r) * 64 + ((ch ^ (r & 7)) << 3);
            gload_lds16(src, &s_k[slot][0][0] + idx * 8);
        }
    };
    auto stage_p = [&](int c, int slot) {
        #pragma unroll
        for (int it = 0; it < 2; ++it) {
            int idx = tid + it * 256;
            int r = idx >> 3, ch = idx & 7;
            int j = jb0 + c * 64 + r; if (j > P_ - 1) j = P_ - 1;
            const u16* src = ph + pbase + (size_t)j * 64 + ((ch ^ (r & 7)) << 3);
            gload_lds16(src, &s_p[slot][0][0] + idx * 8);
        }
    };
    auto bd_chunk = [&](int slot, f32x4* out) {
        #pragma unroll
        for (int nb = 0; nb < 4; ++nb) {
            int pr = nb * 16 + arow;
            f16x8 b0 = *(const f16x8*)(&s_p[slot][0][0] + swz8(pr, kseg * 8));
            f16x8 b1 = *(const f16x8*)(&s_p[slot][0][0] + swz8(pr, 32 + kseg * 8));
            out[nb] = MFMAH(qv[0], b0, out[nb]);
            out[nb] = MFMAH(qv[1], b1, out[nb]);
        }
    };

    stage_k(0, 0); stage_k(1, 1);
    stage_p(0, 0); stage_p(1, 1); stage_p(2, 2);
    __syncthreads();
    f32x4 carry[4] = {};
    bd_chunk(0, carry);
    asm volatile("" ::: "memory");
    __builtin_amdgcn_s_barrier();
    asm volatile("" ::: "memory");

    int ks = 0;
    for (int t = 0; t < 16; ++t) {
        const int k0 = t * 64;
        const int pr = (ks + 1 > 2) ? 0 : ks + 1;
        const int kw = (ks + 2 > 2) ? ks - 1 : ks + 2;

        f16x8 vfr[4][2];
        #pragma unroll
        for (int nt = 0; nt < 4; ++nt) {
            const u16* vp = vt + vtbase + (size_t)(nt * 16 + arow) * T_ + k0 + kseg * 8;
            vfr[nt][0] = *(const f16x8*)vp;
            vfr[nt][1] = *(const f16x8*)(vp + 32);
        }

        if (t < 14) { stage_k(t + 2, kw); stage_p(t + 3, ks); }

        __builtin_amdgcn_s_setprio(1);
        f32x4 ac[4] = {};
        #pragma unroll
        for (int nt = 0; nt < 4; ++nt) {
            int kr = nt * 16 + arow;
            f16x8 b0 = *(const f16x8*)(&s_k[ks][0][0] + swz8(kr, kseg * 8));
            f16x8 b1 = *(const f16x8*)(&s_k[ks][0][0] + swz8(kr, 32 + kseg * 8));
            ac[nt] = MFMAH(qu[0], b0, ac[nt]);
            ac[nt] = MFMAH(qu[1], b1, ac[nt]);
        }
        f32x4 bdn[4] = {};
        bd_chunk(pr, bdn);
        __builtin_amdgcn_s_setprio(0);

        float win[5][4];
        #pragma unroll
        for (int r = 0; r < 4; ++r) {
            if (w == 0)      { win[0][r]=carry[3][r]; win[1][r]=bdn[0][r];   win[2][r]=bdn[1][r];   win[3][r]=bdn[2][r];   win[4][r]=bdn[3][r]; }
            else if (w == 1) { win[0][r]=carry[2][r]; win[1][r]=carry[3][r]; win[2][r]=bdn[0][r];   win[3][r]=bdn[1][r];   win[4][r]=bdn[2][r]; }
            else if (w == 2) { win[0][r]=carry[1][r]; win[1][r]=carry[2][r]; win[2][r]=carry[3][r]; win[3][r]=bdn[0][r];   win[4][r]=bdn[1][r]; }
            else             { win[0][r]=carry[0][r]; win[1][r]=carry[1][r]; win[2][r]=carry[2][r]; win[3][r]=carry[3][r]; win[4][r]=bdn[0][r]; }
        }

        #pragma unroll
        for (int r = 0; r < 4; ++r) {
            int sl  = 15 - (kseg << 2) - r;
            int src = (ln & 48) | ((arow + sl) & 15);
            bool hi = (arow < sl);
            int r16 = kseg * 4 + r;
            #pragma unroll
            for (int nt = 0; nt < 4; ++nt) {
                float sel = hi ? win[nt + 1][r] : win[nt][r];
                float pm = __shfl(sel, src, 64);
                float pv = __expf(ac[nt][r] + pm);
                l_run[r] += pv;
                int kl = nt * 16 + arow;
                s_pp[w][r16][(((kl >> 3) ^ (r16 & 7)) << 3) | (kl & 7)] = f2hbits(pv);
            }
        }
        asm volatile("s_waitcnt lgkmcnt(0)" ::: "memory");
        __builtin_amdgcn_sched_barrier(0);

        f16x8 pa0 = *(const f16x8*)(&s_pp[w][arow][0] + ((kseg ^ (arow & 7)) << 3));
        f16x8 pa1 = *(const f16x8*)(&s_pp[w][arow][0] + (((4 + kseg) ^ (arow & 7)) << 3));
        __builtin_amdgcn_s_setprio(1);
        #pragma unroll
        for (int nt = 0; nt < 4; ++nt) {
            o_[nt] = MFMAH(pa0, vfr[nt][0], o_[nt]);
            o_[nt] = MFMAH(pa1, vfr[nt][1], o_[nt]);
        }
        __builtin_amdgcn_s_setprio(0);

        #pragma unroll
        for (int nb = 0; nb < 4; ++nb) carry[nb] = bdn[nb];

        asm volatile("" ::: "memory");
        __builtin_amdgcn_s_barrier();
        asm volatile("" ::: "memory");
        ks = pr;
    }

    #pragma unroll
    for (int r = 0; r < 4; ++r) {
        float l = l_run[r];
        l += __shfl_xor(l, 1); l += __shfl_xor(l, 2);
        l += __shfl_xor(l, 4); l += __shfl_xor(l, 8);
        l_run[r] = 1.f / l;
    }
    #pragma unroll
    for (int nt = 0; nt < 4; ++nt)
        #pragma unroll
        for (int r = 0; r < 4; ++r) {
            int qrow = q0 + w * 16 + kseg * 4 + r;
            size_t off = ((size_t)(b * T_ + qrow)) * D_ + h * DK_ + nt * 16 + arow;
            ao[off] = f2hbits(o_[nt][r] * l_run[r]);
        }
}

// ---------------------------------------------------------------------------
extern "C" void kernel_launch(void* const* d_in, const int* in_sizes, int n_in,
                              void* d_out, int out_size, void* d_ws, size_t ws_size,
                              hipStream_t stream)
{
    const float* q   = (const float*)d_in[0];
    const float* k   = (const float*)d_in[1];
    const float* v   = (const float*)d_in[2];
    const float* pe  = (const float*)d_in[3];
    const float* Wq  = (const float*)d_in[4];
    const float* bq  = (const float*)d_in[5];
    const float* Wk  = (const float*)d_in[6];
    const float* bk  = (const float*)d_in[7];
    const float* Wv  = (const float*)d_in[8];
    const float* bv  = (const float*)d_in[9];
    const float* Wp  = (const float*)d_in[10];
    const float* pbu = (const float*)d_in[11];
    const float* pbv = (const float*)d_in[12];
    const float* Wo  = (const float*)d_in[13];
    const float* bo  = (const float*)d_in[14];
    float* out = (float*)d_out;

    char* ws = (char*)d_ws;
    const size_t MB = 1024 * 1024;
    const size_t HMB = 512 * 1024;
    // phase 1 (conv_all out / gemm_qkvp in)
    u16* qs  = (u16*)(ws);                 // 4 MB
    u16* ks  = (u16*)(ws + 4 * MB);        // 4 MB
    u16* vs  = (u16*)(ws + 8 * MB);        // 4 MB
    u16* pes = (u16*)(ws + 12 * MB);       // 2.1 MB
    u16* wqs = (u16*)(ws + 17 * MB);
    u16* wks = (u16*)(ws + 17 * MB + HMB);
    u16* wvs = (u16*)(ws + 18 * MB);
    u16* wps = (u16*)(ws + 18 * MB + HMB);
    u16* wos = (u16*)(ws + 19 * MB);
    // phase 2 (gemm_qkvp out / relattn in)
    u16* qub = (u16*)(ws + 20 * MB);       // 4 MB
    u16* qvb = (u16*)(ws + 24 * MB);       // 4 MB
    u16* kh  = (u16*)(ws + 28 * MB);       // 4 MB
    u16* vt  = (u16*)(ws + 32 * MB);       // 4 MB
    u16* ph  = (u16*)(ws + 36 * MB);       // 2.1 MB
    // phase 3 (relattn out / gemm_out in)
    u16* ao  = (u16*)(ws + 38 * MB + HMB); // 4 MB -> ends at 42.5 MB

    dim3 blk(256);
    conv_all<<<dim3(2112), blk, 0, stream>>>(q, k, v, pe, Wq, Wk, Wv, Wp, Wo,
        qs, ks, vs, pes, wqs, wks, wvs, wps, wos);

    gemm_qkvp<<<dim3(4, 112), blk, 0, stream>>>(
        qs, ks, vs, pes, wqs, wks, wvs, wps,
        bq, bk, bv, pbu, pbv, qub, qvb, kh, vt, ph);

    relattn_mfma<<<dim3(512), blk, 0, stream>>>(qub, qvb, kh, vt, ph, ao);

    gemm_out<<<dim3(4, 32), blk, 0, stream>>>(ao, wos, bo, out);
}

// Round 21
// 86.474 us; speedup vs baseline: 1.0075x; 1.0075x over previous
//
#include <hip/hip_runtime.h>
#include <math.h>

typedef unsigned short u16;
typedef _Float16 f16;
typedef __attribute__((ext_vector_type(8))) _Float16 f16x8;
typedef __attribute__((ext_vector_type(4))) float f32x4;

#define B_  4
#define T_  1024
#define D_  512
#define H_  8
#define DK_ 64
#define P_  2047

#define MFMAH(a, b, c) __builtin_amdgcn_mfma_f32_16x16x32_f16(a, b, c, 0, 0, 0)

__device__ __forceinline__ u16 f2hbits(float x) {
    union { f16 h; u16 u; } cv; cv.h = (f16)x; return cv.u;
}

__device__ __forceinline__ void gload_lds16(const u16* g, u16* l) {
    __builtin_amdgcn_global_load_lds(
        (const __attribute__((address_space(1))) void*)g,
        (__attribute__((address_space(3))) void*)l, 16, 0, 0);
}

__device__ __forceinline__ int swz8(int row, int colbase) {   // colbase % 8 == 0
    return row * 64 + (((colbase >> 3) ^ (row & 7)) << 3);
}

// ---------------------------------------------------------------------------
// One-shot conversion: inputs q,k,v,pe and 5 weights -> fp16.
// ---------------------------------------------------------------------------
__global__ __launch_bounds__(256)
void conv_all(const float* __restrict__ q, const float* __restrict__ k,
              const float* __restrict__ v, const float* __restrict__ pe,
              const float* __restrict__ wq, const float* __restrict__ wk,
              const float* __restrict__ wv, const float* __restrict__ wp,
              const float* __restrict__ wo,
              u16* qs, u16* ks, u16* vs, u16* pes,
              u16* wqs, u16* wks, u16* wvs, u16* wps, u16* wos)
{
    const int NQ = 524288;     // float4 chunks in q/k/v
    const int NPE = 262016;    // 2047*512/4
    const int NW = 65536;      // 512*512/4
    const int TOT = 3 * NQ + NPE + 5 * NW;
    for (int i = blockIdx.x * 256 + threadIdx.x; i < TOT; i += gridDim.x * 256) {
        const float* src; u16* dst; int off;
        int j = i;
        if (j < NQ)              { src = q;  dst = qs;  off = j; }
        else if ((j -= NQ) < NQ) { src = k;  dst = ks;  off = j; }
        else if ((j -= NQ) < NQ) { src = v;  dst = vs;  off = j; }
        else if ((j -= NQ) < NPE){ src = pe; dst = pes; off = j; }
        else if ((j -= NPE) < NW){ src = wq; dst = wqs; off = j; }
        else if ((j -= NW) < NW) { src = wk; dst = wks; off = j; }
        else if ((j -= NW) < NW) { src = wv; dst = wvs; off = j; }
        else if ((j -= NW) < NW) { src = wp; dst = wps; off = j; }
        else                     { j -= NW; src = wo; dst = wos; off = j; }
        float4 x = *(const float4*)(src + (size_t)off * 4);
        union { f16 h[4]; uint2 u2; } cv;
        cv.h[0] = (f16)x.x; cv.h[1] = (f16)x.y;
        cv.h[2] = (f16)x.z; cv.h[3] = (f16)x.w;
        *(uint2*)(dst + (size_t)off * 4) = cv.u2;
    }
}

// ---------------------------------------------------------------------------
// FP16 GEMM core, COUNTED-VMCNT DOUBLE-BUFFER (round-14 validated):
// stage tile t+1 BEFORE computing tile t; s_waitcnt vmcnt(8) (never 0 in
// the loop) + raw s_barrier — next tile's 8 gload_lds stay in flight
// across the barrier through the MFMA phase. BM=128 BN=128 BK=64, 64 KB LDS.
// ---------------------------------------------------------------------------
__device__ __forceinline__ void gemm_core(
    const u16* __restrict__ A, const u16* __restrict__ Bw,
    int bm, int bn, int M, f32x4 (&acc)[4][4],
    u16 (&sA)[2][128][64], u16 (&sB)[2][128][64])
{
    const int tid = threadIdx.x;
    const int ln = tid & 63, w = tid >> 6;
    const int arow = ln & 15, kseg = ln >> 4;
    const int wr = w >> 1, wc = w & 1;

    auto stage = [&](int k0, int buf) {
        #pragma unroll
        for (int it = 0; it < 4; ++it) {               // A: 1024 chunks
            int ch = it * 256 + tid;
            int r = ch >> 3, j = ch & 7;
            int rm = bm + r; if (rm > M - 1) rm = M - 1;
            gload_lds16(A + (size_t)rm * 512 + k0 + ((j ^ (r & 7)) << 3),
                        &sA[buf][0][0] + ch * 8);
        }
        #pragma unroll
        for (int it = 0; it < 4; ++it) {               // B: 1024 chunks
            int ch = it * 256 + tid;
            int r = ch >> 3, j = ch & 7;
            gload_lds16(Bw + (size_t)(bn + r) * 512 + k0 + ((j ^ (r & 7)) << 3),
                        &sB[buf][0][0] + ch * 8);
        }
    };

    stage(0, 0);
    for (int t = 0; t < 8; ++t) {
        const int cur = t & 1;
        if (t < 7) {
            stage((t + 1) * 64, cur ^ 1);
            asm volatile("s_waitcnt vmcnt(8)" ::: "memory");
        } else {
            asm volatile("s_waitcnt vmcnt(0)" ::: "memory");
        }
        __builtin_amdgcn_sched_barrier(0);
        __builtin_amdgcn_s_barrier();

        f16x8 af[4][2], bf[4][2];
        #pragma unroll
        for (int mi = 0; mi < 4; ++mi) {
            int row = wr * 64 + mi * 16 + arow;
            #pragma unroll
            for (int kc = 0; kc < 2; ++kc)
                af[mi][kc] = *(const f16x8*)
                    (&sA[cur][row][0] + ((((kc << 2) | kseg) ^ (row & 7)) << 3));
        }
        #pragma unroll
        for (int nj = 0; nj < 4; ++nj) {
            int row = wc * 64 + nj * 16 + arow;
            #pragma unroll
            for (int kc = 0; kc < 2; ++kc)
                bf[nj][kc] = *(const f16x8*)
                    (&sB[cur][row][0] + ((((kc << 2) | kseg) ^ (row & 7)) << 3));
        }
        __builtin_amdgcn_s_setprio(1);
        #pragma unroll
        for (int mi = 0; mi < 4; ++mi)
            #pragma unroll
            for (int nj = 0; nj < 4; ++nj)
                #pragma unroll
                for (int kc = 0; kc < 2; ++kc)
                    acc[mi][nj] = MFMAH(af[mi][kc], bf[nj][kc], acc[mi][nj]);
        __builtin_amdgcn_s_setprio(0);

        asm volatile("" ::: "memory");
        __builtin_amdgcn_s_barrier();   // raw: orders slot reuse, no drain
        asm volatile("" ::: "memory");
    }
}

// ---------------------------------------------------------------------------
// Merged projection GEMM: q/k/v/pe in one launch. grid = (4, 112).
// seg0 emits qu = (q+u)/8 and qv = (q+v)/8 as fp16 head-major.
// ---------------------------------------------------------------------------
__global__ __launch_bounds__(256, 2)
void gemm_qkvp(const u16* __restrict__ qs, const u16* __restrict__ ks,
               const u16* __restrict__ vs, const u16* __restrict__ pes,
               const u16* __restrict__ wqs, const u16* __restrict__ wks,
               const u16* __restrict__ wvs, const u16* __restrict__ wps,
               const float* __restrict__ bq, const float* __restrict__ bk,
               const float* __restrict__ bv,
               const float* __restrict__ pbu, const float* __restrict__ pbv,
               u16* __restrict__ qub, u16* __restrict__ qvb,
               u16* __restrict__ kh, u16* __restrict__ vt, u16* __restrict__ ph)
{
    __shared__ u16 sA[2][128][64];
    __shared__ u16 sB[2][128][64];

    const int by = blockIdx.y;
    const u16 *A, *Bw; const float* bias;
    int seg, bm, M, Tn;
    if (by < 32)      { seg=0; bm=by*128;       A=qs;  Bw=wqs; bias=bq;      M=4096; Tn=T_; }
    else if (by < 64) { seg=1; bm=(by-32)*128;  A=ks;  Bw=wks; bias=bk;      M=4096; Tn=T_; }
    else if (by < 96) { seg=2; bm=(by-64)*128;  A=vs;  Bw=wvs; bias=bv;      M=4096; Tn=T_; }
    else              { seg=3; bm=(by-96)*128;  A=pes; Bw=wps; bias=nullptr; M=P_;   Tn=P_; }
    const int bn = blockIdx.x * 128;

    f32x4 acc[4][4] = {};
    gemm_core(A, Bw, bm, bn, M, acc, sA, sB);

    const int tid = threadIdx.x;
    const int ln = tid & 63, w = tid >> 6;
    const int arow = ln & 15, kseg = ln >> 4;
    const int wr = w >> 1, wc = w & 1;

    float bv0[4];
    #pragma unroll
    for (int nj = 0; nj < 4; ++nj)
        bv0[nj] = bias ? bias[bn + wc * 64 + nj * 16 + arow] : 0.f;

    #pragma unroll
    for (int mi = 0; mi < 4; ++mi)
        #pragma unroll
        for (int r = 0; r < 4; ++r) {
            int m = bm + wr * 64 + mi * 16 + kseg * 4 + r;
            if (m >= M) continue;
            #pragma unroll
            for (int nj = 0; nj < 4; ++nj) {
                int n = bn + wc * 64 + nj * 16 + arow;
                float val = acc[mi][nj][r] + bv0[nj];
                if (seg == 0) {
                    int bb = m >> 10, t = m & 1023;
                    int hh = n >> 6, d = n & 63;
                    size_t off = ((size_t)(bb * H_ + hh) * T_ + t) * 64 + d;
                    qub[off] = f2hbits((val + pbu[hh * 64 + d]) * 0.125f);
                    qvb[off] = f2hbits((val + pbv[hh * 64 + d]) * 0.125f);
                } else if (seg == 2) {
                    int bb = m >> 10, t = m & 1023;
                    int hh = n >> 6, d = n & 63;
                    vt[((size_t)(bb * H_ + hh) * 64 + d) * T_ + t] = f2hbits(val);
                } else {
                    int bb = (Tn == T_) ? (m >> 10) : 0;
                    int t = m - bb * Tn;
                    int hh = n >> 6, d = n & 63;
                    size_t off = ((size_t)(bb * H_ + hh) * Tn + t) * 64 + d;
                    if (seg == 1) kh[off] = f2hbits(val);
                    else          ph[off] = f2hbits(val);
                }
            }
        }
}

// ---------------------------------------------------------------------------
// Output projection (fp32 out)
// ---------------------------------------------------------------------------
__global__ __launch_bounds__(256, 2)
void gemm_out(const u16* __restrict__ A, const u16* __restrict__ Bw,
              const float* __restrict__ bias, float* __restrict__ C)
{
    __shared__ u16 sA[2][128][64];
    __shared__ u16 sB[2][128][64];
    const int bn = blockIdx.x * 128;
    const int bm = blockIdx.y * 128;
    f32x4 acc[4][4] = {};
    gemm_core(A, Bw, bm, bn, 4096, acc, sA, sB);

    const int tid = threadIdx.x;
    const int ln = tid & 63, w = tid >> 6;
    const int arow = ln & 15, kseg = ln >> 4;
    const int wr = w >> 1, wc = w & 1;
    #pragma unroll
    for (int mi = 0; mi < 4; ++mi)
        #pragma unroll
        for (int r = 0; r < 4; ++r) {
            int m = bm + wr * 64 + mi * 16 + kseg * 4 + r;
            #pragma unroll
            for (int nj = 0; nj < 4; ++nj) {
                int n = bn + wc * 64 + nj * 16 + arow;
                C[(size_t)m * 512 + n] = acc[mi][nj][r] + bias[n];
            }
        }
}

// ---------------------------------------------------------------------------
// Fused relative-position attention — round-12/14 validated configuration.
// fp16, fixed-max softmax, counted-vmcnt pipeline (3-slot K/P rings,
// prefetch distance 2, raw s_barrier; V loads issued first each iter).
// 256 threads / 4 waves: occupancy-raising variants all failed —
// more blocks (r8), K-split x2 (r10), 512-thread blocks (r16: 71 us).
// __launch_bounds__(256,2): do NOT raise — (256,4) caps VGPR at 64 ->
// 400 MB scratch spill (round 7, 2.7x slowdown).
// ---------------------------------------------------------------------------
__global__ __launch_bounds__(256, 2)
void relattn_mfma(const u16* __restrict__ qub, const u16* __restrict__ qvb,
                  const u16* __restrict__ kh, const u16* __restrict__ vt,
                  const u16* __restrict__ ph,
                  u16* __restrict__ ao)
{
    __shared__ u16 s_k[3][64][64];      // [slot][k][d]   24 KB ring
    __shared__ u16 s_p[3][64][64];      // [slot][j][d]   24 KB ring
    __shared__ u16 s_pp[4][16][64];     // wave-private P tiles  8 KB

    const int tid = threadIdx.x;
    const int ln  = tid & 63;
    const int w   = tid >> 6;
    const int arow = ln & 15;
    const int kseg = ln >> 4;

    const int lg = ((blockIdx.x & 7) << 6) | (blockIdx.x >> 3);
    const int qt = lg & 15, h = (lg >> 4) & 7, b = lg >> 7;
    const int q0 = qt * 64;

    const size_t kvbase = (size_t)(b * H_ + h) * T_ * 64;
    const size_t vtbase = (size_t)(b * H_ + h) * 64 * T_;
    const size_t pbase  = (size_t)h * P_ * 64;
    const int jb0 = 960 - q0;

    f16x8 qu[2], qv[2];
    {
        const u16* qb = qub + kvbase + (size_t)(q0 + w * 16 + arow) * 64;
        const u16* vb = qvb + kvbase + (size_t)(q0 + w * 16 + arow) * 64;
        #pragma unroll
        for (int c = 0; c < 2; ++c) {
            qu[c] = *(const f16x8*)(qb + c * 32 + kseg * 8);
            qv[c] = *(const f16x8*)(vb + c * 32 + kseg * 8);
        }
    }

    f32x4 o_[4] = {};
    float l_run[4] = {};

    auto stage_k = [&](int kt, int slot) {
        #pragma unroll
        for (int it = 0; it < 2; ++it) {
            int idx = tid + it * 256;
            int r = idx >> 3, ch = idx & 7;
            const u16* src = kh + kvbase + (size_t)(kt * 64 + r) * 64 + ((ch ^ (r & 7)) << 3);
            gload_lds16(src, &s_k[slot][0][0] + idx * 8);
        }
    };
    auto stage_p = [&](int c, int slot) {
        #pragma unroll
        for (int it = 0; it < 2; ++it) {
            int idx = tid + it * 256;
            int r = idx >> 3, ch = idx & 7;
            int j = jb0 + c * 64 + r; if (j > P_ - 1) j = P_ - 1;
            const u16* src = ph + pbase + (size_t)j * 64 + ((ch ^ (r & 7)) << 3);
            gload_lds16(src, &s_p[slot][0][0] + idx * 8);
        }
    };
    auto bd_chunk = [&](int slot, f32x4* out) {
        #pragma unroll
        for (int nb = 0; nb < 4; ++nb) {
            int pr = nb * 16 + arow;
            f16x8 b0 = *(const f16x8*)(&s_p[slot][0][0] + swz8(pr, kseg * 8));
            f16x8 b1 = *(const f16x8*)(&s_p[slot][0][0] + swz8(pr, 32 + kseg * 8));
            out[nb] = MFMAH(qv[0], b0, out[nb]);
            out[nb] = MFMAH(qv[1], b1, out[nb]);
        }
    };

    stage_k(0, 0); stage_k(1, 1);
    stage_p(0, 0); stage_p(1, 1); stage_p(2, 2);
    __syncthreads();
    f32x4 carry[4] = {};
    bd_chunk(0, carry);
    asm volatile("" ::: "memory");
    __builtin_amdgcn_s_barrier();
    asm volatile("" ::: "memory");

    int ks = 0;
    for (int t = 0; t < 16; ++t) {
        const int k0 = t * 64;
        const int pr = (ks + 1 > 2) ? 0 : ks + 1;
        const int kw = (ks + 2 > 2) ? ks - 1 : ks + 2;

        f16x8 vfr[4][2];
        #pragma unroll
        for (int nt = 0; nt < 4; ++nt) {
            const u16* vp = vt + vtbase + (size_t)(nt * 16 + arow) * T_ + k0 + kseg * 8;
            vfr[nt][0] = *(const f16x8*)vp;
            vfr[nt][1] = *(const f16x8*)(vp + 32);
        }

        if (t < 14) { stage_k(t + 2, kw); stage_p(t + 3, ks); }

        __builtin_amdgcn_s_setprio(1);
        f32x4 ac[4] = {};
        #pragma unroll
        for (int nt = 0; nt < 4; ++nt) {
            int kr = nt * 16 + arow;
            f16x8 b0 = *(const f16x8*)(&s_k[ks][0][0] + swz8(kr, kseg * 8));
            f16x8 b1 = *(const f16x8*)(&s_k[ks][0][0] + swz8(kr, 32 + kseg * 8));
            ac[nt] = MFMAH(qu[0], b0, ac[nt]);
            ac[nt] = MFMAH(qu[1], b1, ac[nt]);
        }
        f32x4 bdn[4] = {};
        bd_chunk(pr, bdn);
        __builtin_amdgcn_s_setprio(0);

        float win[5][4];
        #pragma unroll
        for (int r = 0; r < 4; ++r) {
            if (w == 0)      { win[0][r]=carry[3][r]; win[1][r]=bdn[0][r];   win[2][r]=bdn[1][r];   win[3][r]=bdn[2][r];   win[4][r]=bdn[3][r]; }
            else if (w == 1) { win[0][r]=carry[2][r]; win[1][r]=carry[3][r]; win[2][r]=bdn[0][r];   win[3][r]=bdn[1][r];   win[4][r]=bdn[2][r]; }
            else if (w == 2) { win[0][r]=carry[1][r]; win[1][r]=carry[2][r]; win[2][r]=carry[3][r]; win[3][r]=bdn[0][r];   win[4][r]=bdn[1][r]; }
            else             { win[0][r]=carry[0][r]; win[1][r]=carry[1][r]; win[2][r]=carry[2][r]; win[3][r]=carry[3][r]; win[4][r]=bdn[0][r]; }
        }

        #pragma unroll
        for (int r = 0; r < 4; ++r) {
            int sl  = 15 - (kseg << 2) - r;
            int src = (ln & 48) | ((arow + sl) & 15);
            bool hi = (arow < sl);
            int r16 = kseg * 4 + r;
            #pragma unroll
            for (int nt = 0; nt < 4; ++nt) {
                float sel = hi ? win[nt + 1][r] : win[nt][r];
                float pm = __shfl(sel, src, 64);
                float pv = __expf(ac[nt][r] + pm);
                l_run[r] += pv;
                int kl = nt * 16 + arow;
                s_pp[w][r16][(((kl >> 3) ^ (r16 & 7)) << 3) | (kl & 7)] = f2hbits(pv);
            }
        }
        asm volatile("s_waitcnt lgkmcnt(0)" ::: "memory");
        __builtin_amdgcn_sched_barrier(0);

        f16x8 pa0 = *(const f16x8*)(&s_pp[w][arow][0] + ((kseg ^ (arow & 7)) << 3));
        f16x8 pa1 = *(const f16x8*)(&s_pp[w][arow][0] + (((4 + kseg) ^ (arow & 7)) << 3));
        __builtin_amdgcn_s_setprio(1);
        #pragma unroll
        for (int nt = 0; nt < 4; ++nt) {
            o_[nt] = MFMAH(pa0, vfr[nt][0], o_[nt]);
            o_[nt] = MFMAH(pa1, vfr[nt][1], o_[nt]);
        }
        __builtin_amdgcn_s_setprio(0);

        #pragma unroll
        for (int nb = 0; nb < 4; ++nb) carry[nb] = bdn[nb];

        asm volatile("" ::: "memory");
        __builtin_amdgcn_s_barrier();
        asm volatile("" ::: "memory");
        ks = pr;
    }

    #pragma unroll
    for (int r = 0; r < 4; ++r) {
        float l = l_run[r];
        l += __shfl_xor(l, 1); l += __shfl_xor(l, 2);
        l += __shfl_xor(l, 4); l += __shfl_xor(l, 8);
        l_run[r] = 1.f / l;
    }
    #pragma unroll
    for (int nt = 0; nt < 4; ++nt)
        #pragma unroll
        for (int r = 0; r < 4; ++r) {
            int qrow = q0 + w * 16 + kseg * 4 + r;
            size_t off = ((size_t)(b * T_ + qrow)) * D_ + h * DK_ + nt * 16 + arow;
            ao[off] = f2hbits(o_[nt][r] * l_run[r]);
        }
}

// ---------------------------------------------------------------------------
extern "C" void kernel_launch(void* const* d_in, const int* in_sizes, int n_in,
                              void* d_out, int out_size, void* d_ws, size_t ws_size,
                              hipStream_t stream)
{
    const float* q   = (const float*)d_in[0];
    const float* k   = (const float*)d_in[1];
    const float* v   = (const float*)d_in[2];
    const float* pe  = (const float*)d_in[3];
    const float* Wq  = (const float*)d_in[4];
    const float* bq  = (const float*)d_in[5];
    const float* Wk  = (const float*)d_in[6];
    const float* bk  = (const float*)d_in[7];
    const float* Wv  = (const float*)d_in[8];
    const float* bv  = (const float*)d_in[9];
    const float* Wp  = (const float*)d_in[10];
    const float* pbu = (const float*)d_in[11];
    const float* pbv = (const float*)d_in[12];
    const float* Wo  = (const float*)d_in[13];
    const float* bo  = (const float*)d_in[14];
    float* out = (float*)d_out;

    char* ws = (char*)d_ws;
    const size_t MB = 1024 * 1024;
    const size_t HMB = 512 * 1024;
    // phase 1 (conv_all out / gemm_qkvp in)
    u16* qs  = (u16*)(ws);                 // 4 MB
    u16* ks  = (u16*)(ws + 4 * MB);        // 4 MB
    u16* vs  = (u16*)(ws + 8 * MB);        // 4 MB
    u16* pes = (u16*)(ws + 12 * MB);       // 2.1 MB
    u16* wqs = (u16*)(ws + 17 * MB);
    u16* wks = (u16*)(ws + 17 * MB + HMB);
    u16* wvs = (u16*)(ws + 18 * MB);
    u16* wps = (u16*)(ws + 18 * MB + HMB);
    u16* wos = (u16*)(ws + 19 * MB);
    // phase 2 (gemm_qkvp out / relattn in)
    u16* qub = (u16*)(ws + 20 * MB);       // 4 MB
    u16* qvb = (u16*)(ws + 24 * MB);       // 4 MB
    u16* kh  = (u16*)(ws + 28 * MB);       // 4 MB
    u16* vt  = (u16*)(ws + 32 * MB);       // 4 MB
    u16* ph  = (u16*)(ws + 36 * MB);       // 2.1 MB
    // phase 3 (relattn out / gemm_out in)
    u16* ao  = (u16*)(ws + 38 * MB + HMB); // 4 MB -> ends at 42.5 MB

    dim3 blk(256);
    conv_all<<<dim3(2048), blk, 0, stream>>>(q, k, v, pe, Wq, Wk, Wv, Wp, Wo,
        qs, ks, vs, pes, wqs, wks, wvs, wps, wos);

    gemm_qkvp<<<dim3(4, 112), blk, 0, stream>>>(
        qs, ks, vs, pes, wqs, wks, wvs, wps,
        bq, bk, bv, pbu, pbv, qub, qvb, kh, vt, ph);

    relattn_mfma<<<dim3(512), blk, 0, stream>>>(qub, qvb, kh, vt, ph, ao);

    gemm_out<<<dim3(4, 32), blk, 0, stream>>>(ao, wos, bo, out);
}

// Round 22
// 86.165 us; speedup vs baseline: 1.0111x; 1.0036x over previous
//
#include <hip/hip_runtime.h>
#include <math.h>

typedef unsigned short u16;
typedef _Float16 f16;
typedef __attribute__((ext_vector_type(8))) _Float16 f16x8;
typedef __attribute__((ext_vector_type(4))) float f32x4;

#define B_  4
#define T_  1024
#define D_  512
#define H_  8
#define DK_ 64
#define P_  2047

#define MFMAH(a, b, c) __builtin_amdgcn_mfma_f32_16x16x32_f16(a, b, c, 0, 0, 0)

__device__ __forceinline__ u16 f2hbits(float x) {
    union { f16 h; u16 u; } cv; cv.h = (f16)x; return cv.u;
}

__device__ __forceinline__ void gload_lds16(const u16* g, u16* l) {
    __builtin_amdgcn_global_load_lds(
        (const __attribute__((address_space(1))) void*)g,
        (__attribute__((address_space(3))) void*)l, 16, 0, 0);
}

__device__ __forceinline__ int swz8(int row, int colbase) {   // colbase % 8 == 0
    return row * 64 + (((colbase >> 3) ^ (row & 7)) << 3);
}

// ---------------------------------------------------------------------------
// One-shot conversion: inputs q,k,v,pe and 5 weights -> fp16.
// ---------------------------------------------------------------------------
__global__ __launch_bounds__(256)
void conv_all(const float* __restrict__ q, const float* __restrict__ k,
              const float* __restrict__ v, const float* __restrict__ pe,
              const float* __restrict__ wq, const float* __restrict__ wk,
              const float* __restrict__ wv, const float* __restrict__ wp,
              const float* __restrict__ wo,
              u16* qs, u16* ks, u16* vs, u16* pes,
              u16* wqs, u16* wks, u16* wvs, u16* wps, u16* wos)
{
    const int NQ = 524288;     // float4 chunks in q/k/v
    const int NPE = 262016;    // 2047*512/4
    const int NW = 65536;      // 512*512/4
    const int TOT = 3 * NQ + NPE + 5 * NW;
    for (int i = blockIdx.x * 256 + threadIdx.x; i < TOT; i += gridDim.x * 256) {
        const float* src; u16* dst; int off;
        int j = i;
        if (j < NQ)              { src = q;  dst = qs;  off = j; }
        else if ((j -= NQ) < NQ) { src = k;  dst = ks;  off = j; }
        else if ((j -= NQ) < NQ) { src = v;  dst = vs;  off = j; }
        else if ((j -= NQ) < NPE){ src = pe; dst = pes; off = j; }
        else if ((j -= NPE) < NW){ src = wq; dst = wqs; off = j; }
        else if ((j -= NW) < NW) { src = wk; dst = wks; off = j; }
        else if ((j -= NW) < NW) { src = wv; dst = wvs; off = j; }
        else if ((j -= NW) < NW) { src = wp; dst = wps; off = j; }
        else                     { j -= NW; src = wo; dst = wos; off = j; }
        float4 x = *(const float4*)(src + (size_t)off * 4);
        union { f16 h[4]; uint2 u2; } cv;
        cv.h[0] = (f16)x.x; cv.h[1] = (f16)x.y;
        cv.h[2] = (f16)x.z; cv.h[3] = (f16)x.w;
        *(uint2*)(dst + (size_t)off * 4) = cv.u2;
    }
}

// ---------------------------------------------------------------------------
// FP16 GEMM core, COUNTED-VMCNT DOUBLE-BUFFER (round-14 validated):
// stage tile t+1 BEFORE computing tile t; s_waitcnt vmcnt(8) (never 0 in
// the loop) + raw s_barrier — next tile's 8 gload_lds stay in flight
// across the barrier through the MFMA phase. BM=128 BN=128 BK=64, 64 KB LDS.
// ---------------------------------------------------------------------------
__device__ __forceinline__ void gemm_core(
    const u16* __restrict__ A, const u16* __restrict__ Bw,
    int bm, int bn, int M, f32x4 (&acc)[4][4],
    u16 (&sA)[2][128][64], u16 (&sB)[2][128][64])
{
    const int tid = threadIdx.x;
    const int ln = tid & 63, w = tid >> 6;
    const int arow = ln & 15, kseg = ln >> 4;
    const int wr = w >> 1, wc = w & 1;

    auto stage = [&](int k0, int buf) {
        #pragma unroll
        for (int it = 0; it < 4; ++it) {               // A: 1024 chunks
            int ch = it * 256 + tid;
            int r = ch >> 3, j = ch & 7;
            int rm = bm + r; if (rm > M - 1) rm = M - 1;
            gload_lds16(A + (size_t)rm * 512 + k0 + ((j ^ (r & 7)) << 3),
                        &sA[buf][0][0] + ch * 8);
        }
        #pragma unroll
        for (int it = 0; it < 4; ++it) {               // B: 1024 chunks
            int ch = it * 256 + tid;
            int r = ch >> 3, j = ch & 7;
            gload_lds16(Bw + (size_t)(bn + r) * 512 + k0 + ((j ^ (r & 7)) << 3),
                        &sB[buf][0][0] + ch * 8);
        }
    };

    stage(0, 0);
    for (int t = 0; t < 8; ++t) {
        const int cur = t & 1;
        if (t < 7) {
            stage((t + 1) * 64, cur ^ 1);
            asm volatile("s_waitcnt vmcnt(8)" ::: "memory");
        } else {
            asm volatile("s_waitcnt vmcnt(0)" ::: "memory");
        }
        __builtin_amdgcn_sched_barrier(0);
        __builtin_amdgcn_s_barrier();

        f16x8 af[4][2], bf[4][2];
        #pragma unroll
        for (int mi = 0; mi < 4; ++mi) {
            int row = wr * 64 + mi * 16 + arow;
            #pragma unroll
            for (int kc = 0; kc < 2; ++kc)
                af[mi][kc] = *(const f16x8*)
                    (&sA[cur][row][0] + ((((kc << 2) | kseg) ^ (row & 7)) << 3));
        }
        #pragma unroll
        for (int nj = 0; nj < 4; ++nj) {
            int row = wc * 64 + nj * 16 + arow;
            #pragma unroll
            for (int kc = 0; kc < 2; ++kc)
                bf[nj][kc] = *(const f16x8*)
                    (&sB[cur][row][0] + ((((kc << 2) | kseg) ^ (row & 7)) << 3));
        }
        __builtin_amdgcn_s_setprio(1);
        #pragma unroll
        for (int mi = 0; mi < 4; ++mi)
            #pragma unroll
            for (int nj = 0; nj < 4; ++nj)
                #pragma unroll
                for (int kc = 0; kc < 2; ++kc)
                    acc[mi][nj] = MFMAH(af[mi][kc], bf[nj][kc], acc[mi][nj]);
        __builtin_amdgcn_s_setprio(0);

        asm volatile("" ::: "memory");
        __builtin_amdgcn_s_barrier();   // raw: orders slot reuse, no drain
        asm volatile("" ::: "memory");
    }
}

// ---------------------------------------------------------------------------
// Merged projection GEMM: q/k/v/pe in one launch. grid = (4, 112).
// seg0 emits qu = (q+u)/8 and qv = (q+v)/8 as fp16 head-major.
// ---------------------------------------------------------------------------
__global__ __launch_bounds__(256, 2)
void gemm_qkvp(const u16* __restrict__ qs, const u16* __restrict__ ks,
               const u16* __restrict__ vs, const u16* __restrict__ pes,
               const u16* __restrict__ wqs, const u16* __restrict__ wks,
               const u16* __restrict__ wvs, const u16* __restrict__ wps,
               const float* __restrict__ bq, const float* __restrict__ bk,
               const float* __restrict__ bv,
               const float* __restrict__ pbu, const float* __restrict__ pbv,
               u16* __restrict__ qub, u16* __restrict__ qvb,
               u16* __restrict__ kh, u16* __restrict__ vt, u16* __restrict__ ph)
{
    __shared__ u16 sA[2][128][64];
    __shared__ u16 sB[2][128][64];

    const int by = blockIdx.y;
    const u16 *A, *Bw; const float* bias;
    int seg, bm, M, Tn;
    if (by < 32)      { seg=0; bm=by*128;       A=qs;  Bw=wqs; bias=bq;      M=4096; Tn=T_; }
    else if (by < 64) { seg=1; bm=(by-32)*128;  A=ks;  Bw=wks; bias=bk;      M=4096; Tn=T_; }
    else if (by < 96) { seg=2; bm=(by-64)*128;  A=vs;  Bw=wvs; bias=bv;      M=4096; Tn=T_; }
    else              { seg=3; bm=(by-96)*128;  A=pes; Bw=wps; bias=nullptr; M=P_;   Tn=P_; }
    const int bn = blockIdx.x * 128;

    f32x4 acc[4][4] = {};
    gemm_core(A, Bw, bm, bn, M, acc, sA, sB);

    const int tid = threadIdx.x;
    const int ln = tid & 63, w = tid >> 6;
    const int arow = ln & 15, kseg = ln >> 4;
    const int wr = w >> 1, wc = w & 1;

    float bv0[4];
    #pragma unroll
    for (int nj = 0; nj < 4; ++nj)
        bv0[nj] = bias ? bias[bn + wc * 64 + nj * 16 + arow] : 0.f;

    #pragma unroll
    for (int mi = 0; mi < 4; ++mi)
        #pragma unroll
        for (int r = 0; r < 4; ++r) {
            int m = bm + wr * 64 + mi * 16 + kseg * 4 + r;
            if (m >= M) continue;
            #pragma unroll
            for (int nj = 0; nj < 4; ++nj) {
                int n = bn + wc * 64 + nj * 16 + arow;
                float val = acc[mi][nj][r] + bv0[nj];
                if (seg == 0) {
                    int bb = m >> 10, t = m & 1023;
                    int hh = n >> 6, d = n & 63;
                    size_t off = ((size_t)(bb * H_ + hh) * T_ + t) * 64 + d;
                    qub[off] = f2hbits((val + pbu[hh * 64 + d]) * 0.125f);
                    qvb[off] = f2hbits((val + pbv[hh * 64 + d]) * 0.125f);
                } else if (seg == 2) {
                    int bb = m >> 10, t = m & 1023;
                    int hh = n >> 6, d = n & 63;
                    vt[((size_t)(bb * H_ + hh) * 64 + d) * T_ + t] = f2hbits(val);
                } else {
                    int bb = (Tn == T_) ? (m >> 10) : 0;
                    int t = m - bb * Tn;
                    int hh = n >> 6, d = n & 63;
                    size_t off = ((size_t)(bb * H_ + hh) * Tn + t) * 64 + d;
                    if (seg == 1) kh[off] = f2hbits(val);
                    else          ph[off] = f2hbits(val);
                }
            }
        }
}

// ---------------------------------------------------------------------------
// Output projection (fp32 out)
// ---------------------------------------------------------------------------
__global__ __launch_bounds__(256, 2)
void gemm_out(const u16* __restrict__ A, const u16* __restrict__ Bw,
              const float* __restrict__ bias, float* __restrict__ C)
{
    __shared__ u16 sA[2][128][64];
    __shared__ u16 sB[2][128][64];
    const int bn = blockIdx.x * 128;
    const int bm = blockIdx.y * 128;
    f32x4 acc[4][4] = {};
    gemm_core(A, Bw, bm, bn, 4096, acc, sA, sB);

    const int tid = threadIdx.x;
    const int ln = tid & 63, w = tid >> 6;
    const int arow = ln & 15, kseg = ln >> 4;
    const int wr = w >> 1, wc = w & 1;
    #pragma unroll
    for (int mi = 0; mi < 4; ++mi)
        #pragma unroll
        for (int r = 0; r < 4; ++r) {
            int m = bm + wr * 64 + mi * 16 + kseg * 4 + r;
            #pragma unroll
            for (int nj = 0; nj < 4; ++nj) {
                int n = bn + wc * 64 + nj * 16 + arow;
                C[(size_t)m * 512 + n] = acc[mi][nj][r] + bias[n];
            }
        }
}

// ---------------------------------------------------------------------------
// Fused relative-position attention — round-12/14 validated configuration.
// fp16, fixed-max softmax, counted-vmcnt pipeline (3-slot K/P rings,
// prefetch distance 2, raw s_barrier; V loads issued first each iter).
// 256 threads / 4 waves: occupancy-raising variants all failed —
// more blocks (r8), K-split x2 (r10), 512-thread blocks (r16: 71 us).
// __launch_bounds__(256,2): do NOT raise — (256,4) caps VGPR at 64 ->
// 400 MB scratch spill (round 7, 2.7x slowdown).
// ---------------------------------------------------------------------------
__global__ __launch_bounds__(256, 2)
void relattn_mfma(const u16* __restrict__ qub, const u16* __restrict__ qvb,
                  const u16* __restrict__ kh, const u16* __restrict__ vt,
                  const u16* __restrict__ ph,
                  u16* __restrict__ ao)
{
    __shared__ u16 s_k[3][64][64];      // [slot][k][d]   24 KB ring
    __shared__ u16 s_p[3][64][64];      // [slot][j][d]   24 KB ring
    __shared__ u16 s_pp[4][16][64];     // wave-private P tiles  8 KB

    const int tid = threadIdx.x;
    const int ln  = tid & 63;
    const int w   = tid >> 6;
    const int arow = ln & 15;
    const int kseg = ln >> 4;

    const int lg = ((blockIdx.x & 7) << 6) | (blockIdx.x >> 3);
    const int qt = lg & 15, h = (lg >> 4) & 7, b = lg >> 7;
    const int q0 = qt * 64;

    const size_t kvbase = (size_t)(b * H_ + h) * T_ * 64;
    const size_t vtbase = (size_t)(b * H_ + h) * 64 * T_;
    const size_t pbase  = (size_t)h * P_ * 64;
    const int jb0 = 960 - q0;

    f16x8 qu[2], qv[2];
    {
        const u16* qb = qub + kvbase + (size_t)(q0 + w * 16 + arow) * 64;
        const u16* vb = qvb + kvbase + (size_t)(q0 + w * 16 + arow) * 64;
        #pragma unroll
        for (int c = 0; c < 2; ++c) {
            qu[c] = *(const f16x8*)(qb + c * 32 + kseg * 8);
            qv[c] = *(const f16x8*)(vb + c * 32 + kseg * 8);
        }
    }

    f32x4 o_[4] = {};
    float l_run[4] = {};

    auto stage_k = [&](int kt, int slot) {
        #pragma unroll
        for (int it = 0; it < 2; ++it) {
            int idx = tid + it * 256;
            int r = idx >> 3, ch = idx & 7;
            const u16* src = kh + kvbase + (size_t)(kt * 64 + r) * 64 + ((ch ^ (r & 7)) << 3);
            gload_lds16(src, &s_k[slot][0][0] + idx * 8);
        }
    };
    auto stage_p = [&](int c, int slot) {
        #pragma unroll
        for (int it = 0; it < 2; ++it) {
            int idx = tid + it * 256;
            int r = idx >> 3, ch = idx & 7;
            int j = jb0 + c * 64 + r; if (j > P_ - 1) j = P_ - 1;
            const u16* src = ph + pbase + (size_t)j * 64 + ((ch ^ (r & 7)) << 3);
            gload_lds16(src, &s_p[slot][0][0] + idx * 8);
        }
    };
    auto bd_chunk = [&](int slot, f32x4* out) {
        #pragma unroll
        for (int nb = 0; nb < 4; ++nb) {
            int pr = nb * 16 + arow;
            f16x8 b0 = *(const f16x8*)(&s_p[slot][0][0] + swz8(pr, kseg * 8));
            f16x8 b1 = *(const f16x8*)(&s_p[slot][0][0] + swz8(pr, 32 + kseg * 8));
            out[nb] = MFMAH(qv[0], b0, out[nb]);
            out[nb] = MFMAH(qv[1], b1, out[nb]);
        }
    };

    stage_k(0, 0); stage_k(1, 1);
    stage_p(0, 0); stage_p(1, 1); stage_p(2, 2);
    __syncthreads();
    f32x4 carry[4] = {};
    bd_chunk(0, carry);
    asm volatile("" ::: "memory");
    __builtin_amdgcn_s_barrier();
    asm volatile("" ::: "memory");

    int ks = 0;
    for (int t = 0; t < 16; ++t) {
        const int k0 = t * 64;
        const int pr = (ks + 1 > 2) ? 0 : ks + 1;
        const int kw = (ks + 2 > 2) ? ks - 1 : ks + 2;

        f16x8 vfr[4][2];
        #pragma unroll
        for (int nt = 0; nt < 4; ++nt) {
            const u16* vp = vt + vtbase + (size_t)(nt * 16 + arow) * T_ + k0 + kseg * 8;
            vfr[nt][0] = *(const f16x8*)vp;
            vfr[nt][1] = *(const f16x8*)(vp + 32);
        }

        if (t < 14) { stage_k(t + 2, kw); stage_p(t + 3, ks); }

        __builtin_amdgcn_s_setprio(1);
        f32x4 ac[4] = {};
        #pragma unroll
        for (int nt = 0; nt < 4; ++nt) {
            int kr = nt * 16 + arow;
            f16x8 b0 = *(const f16x8*)(&s_k[ks][0][0] + swz8(kr, kseg * 8));
            f16x8 b1 = *(const f16x8*)(&s_k[ks][0][0] + swz8(kr, 32 + kseg * 8));
            ac[nt] = MFMAH(qu[0], b0, ac[nt]);
            ac[nt] = MFMAH(qu[1], b1, ac[nt]);
        }
        f32x4 bdn[4] = {};
        bd_chunk(pr, bdn);
        __builtin_amdgcn_s_setprio(0);

        float win[5][4];
        #pragma unroll
        for (int r = 0; r < 4; ++r) {
            if (w == 0)      { win[0][r]=carry[3][r]; win[1][r]=bdn[0][r];   win[2][r]=bdn[1][r];   win[3][r]=bdn[2][r];   win[4][r]=bdn[3][r]; }
            else if (w == 1) { win[0][r]=carry[2][r]; win[1][r]=carry[3][r]; win[2][r]=bdn[0][r];   win[3][r]=bdn[1][r];   win[4][r]=bdn[2][r]; }
            else if (w == 2) { win[0][r]=carry[1][r]; win[1][r]=carry[2][r]; win[2][r]=carry[3][r]; win[3][r]=bdn[0][r];   win[4][r]=bdn[1][r]; }
            else             { win[0][r]=carry[0][r]; win[1][r]=carry[1][r]; win[2][r]=carry[2][r]; win[3][r]=carry[3][r]; win[4][r]=bdn[0][r]; }
        }

        #pragma unroll
        for (int r = 0; r < 4; ++r) {
            int sl  = 15 - (kseg << 2) - r;
            int src = (ln & 48) | ((arow + sl) & 15);
            bool hi = (arow < sl);
            int r16 = kseg * 4 + r;
            #pragma unroll
            for (int nt = 0; nt < 4; ++nt) {
                float sel = hi ? win[nt + 1][r] : win[nt][r];
                float pm = __shfl(sel, src, 64);
                float pv = __expf(ac[nt][r] + pm);
                l_run[r] += pv;
                int kl = nt * 16 + arow;
                s_pp[w][r16][(((kl >> 3) ^ (r16 & 7)) << 3) | (kl & 7)] = f2hbits(pv);
            }
        }
        asm volatile("s_waitcnt lgkmcnt(0)" ::: "memory");
        __builtin_amdgcn_sched_barrier(0);

        f16x8 pa0 = *(const f16x8*)(&s_pp[w][arow][0] + ((kseg ^ (arow & 7)) << 3));
        f16x8 pa1 = *(const f16x8*)(&s_pp[w][arow][0] + (((4 + kseg) ^ (arow & 7)) << 3));
        __builtin_amdgcn_s_setprio(1);
        #pragma unroll
        for (int nt = 0; nt < 4; ++nt) {
            o_[nt] = MFMAH(pa0, vfr[nt][0], o_[nt]);
            o_[nt] = MFMAH(pa1, vfr[nt][1], o_[nt]);
        }
        __builtin_amdgcn_s_setprio(0);

        #pragma unroll
        for (int nb = 0; nb < 4; ++nb) carry[nb] = bdn[nb];

        asm volatile("" ::: "memory");
        __builtin_amdgcn_s_barrier();
        asm volatile("" ::: "memory");
        ks = pr;
    }

    #pragma unroll
    for (int r = 0; r < 4; ++r) {
        float l = l_run[r];
        l += __shfl_xor(l, 1); l += __shfl_xor(l, 2);
        l += __shfl_xor(l, 4); l += __shfl_xor(l, 8);
        l_run[r] = 1.f / l;
    }
    #pragma unroll
    for (int nt = 0; nt < 4; ++nt)
        #pragma unroll
        for (int r = 0; r < 4; ++r) {
            int qrow = q0 + w * 16 + kseg * 4 + r;
            size_t off = ((size_t)(b * T_ + qrow)) * D_ + h * DK_ + nt * 16 + arow;
            ao[off] = f2hbits(o_[nt][r] * l_run[r]);
        }
}

// ---------------------------------------------------------------------------
extern "C" void kernel_launch(void* const* d_in, const int* in_sizes, int n_in,
                              void* d_out, int out_size, void* d_ws, size_t ws_size,
                              hipStream_t stream)
{
    const float* q   = (const float*)d_in[0];
    const float* k   = (const float*)d_in[1];
    const float* v   = (const float*)d_in[2];
    const float* pe  = (const float*)d_in[3];
    const float* Wq  = (const float*)d_in[4];
    const float* bq  = (const float*)d_in[5];
    const float* Wk  = (const float*)d_in[6];
    const float* bk  = (const float*)d_in[7];
    const float* Wv  = (const float*)d_in[8];
    const float* bv  = (const float*)d_in[9];
    const float* Wp  = (const float*)d_in[10];
    const float* pbu = (const float*)d_in[11];
    const float* pbv = (const float*)d_in[12];
    const float* Wo  = (const float*)d_in[13];
    const float* bo  = (const float*)d_in[14];
    float* out = (float*)d_out;

    char* ws = (char*)d_ws;
    const size_t MB = 1024 * 1024;
    const size_t HMB = 512 * 1024;
    // phase 1 (conv_all out / gemm_qkvp in)
    u16* qs  = (u16*)(ws);                 // 4 MB
    u16* ks  = (u16*)(ws + 4 * MB);        // 4 MB
    u16* vs  = (u16*)(ws + 8 * MB);        // 4 MB
    u16* pes = (u16*)(ws + 12 * MB);       // 2.1 MB
    u16* wqs = (u16*)(ws + 17 * MB);
    u16* wks = (u16*)(ws + 17 * MB + HMB);
    u16* wvs = (u16*)(ws + 18 * MB);
    u16* wps = (u16*)(ws + 18 * MB + HMB);
    u16* wos = (u16*)(ws + 19 * MB);
    // phase 2 (gemm_qkvp out / relattn in)
    u16* qub = (u16*)(ws + 20 * MB);       // 4 MB
    u16* qvb = (u16*)(ws + 24 * MB);       // 4 MB
    u16* kh  = (u16*)(ws + 28 * MB);       // 4 MB
    u16* vt  = (u16*)(ws + 32 * MB);       // 4 MB
    u16* ph  = (u16*)(ws + 36 * MB);       // 2.1 MB
    // phase 3 (relattn out / gemm_out in)
    u16* ao  = (u16*)(ws + 38 * MB + HMB); // 4 MB -> ends at 42.5 MB

    dim3 blk(256);
    conv_all<<<dim3(2048), blk, 0, stream>>>(q, k, v, pe, Wq, Wk, Wv, Wp, Wo,
        qs, ks, vs, pes, wqs, wks, wvs, wps, wos);

    gemm_qkvp<<<dim3(4, 112), blk, 0, stream>>>(
        qs, ks, vs, pes, wqs, wks, wvs, wps,
        bq, bk, bv, pbu, pbv, qub, qvb, kh, vt, ph);

    relattn_mfma<<<dim3(512), blk, 0, stream>>>(qub, qvb, kh, vt, ph, ao);

    gemm_out<<<dim3(4, 32), blk, 0, stream>>>(ao, wos, bo, out);
}